// Round 1
// baseline (394.509 us; speedup 1.0000x reference)
//
#include <hip/hip_runtime.h>
#include <limits.h>

#define HH 128
#define WW_ 128
#define HW 16384
#define NB 16
#define CF 192
#define H2 64
#define W2 64
#define NRUN 8192     // max runs: 128 rows * 64 runs/row
#define NCOMP 4096    // max 8-connected components in 128x128

typedef float vf4 __attribute__((ext_vector_type(4)));
typedef unsigned long long ull;

// ---------------------------------------------------------------------------
// Union-find on LDS parent array indexed by run id = (row<<6) | runIdxInRow.
// Links always go high->low id -> chains strictly decrease -> concurrent
// path halving is safe and terminating.
// ---------------------------------------------------------------------------

__device__ inline int uf_find(int* par, int x) {
    volatile int* vp = (volatile int*)par;
    int p = vp[x];
    while (p != x) {
        int g = vp[p];
        vp[x] = g;      // path halving: writes an ancestor, safe under races
        x = g;
        p = vp[x];
    }
    return x;
}

__device__ inline void uf_union(int* par, int a, int b) {
    int ra = uf_find(par, a);
    int rb = uf_find(par, b);
    while (ra != rb) {
        if (ra < rb) { int t = ra; ra = rb; rb = t; }   // link larger -> smaller
        int old = atomicCAS(&par[ra], ra, rb);
        if (old == ra) return;
        ra = uf_find(par, old);
        rb = uf_find(par, rb);
    }
}

// ---------------------------------------------------------------------------
// 128-bit row mask helpers (lo = cols 0..63, hi = cols 64..127)
// ---------------------------------------------------------------------------

__device__ inline int getbit2(ull lo, ull hi, int c) {
    return (int)(((c < 64) ? (lo >> c) : (hi >> (c - 64))) & 1ULL);
}

__device__ inline int leading_ones(ull v) {
    ull nv = ~v;
    return (nv == 0ULL) ? 64 : __clzll(nv);
}

__device__ inline int trailing_ones(ull v) {
    ull nv = ~v;
    return (nv == 0ULL) ? 64 : (__ffsll(nv) - 1);
}

// column of the start of the fg run containing column c (bit c must be set)
__device__ inline int run_start_col(ull lo, ull hi, int c) {
    if (c < 64) {
        int ones = leading_ones(lo << (63 - c));   // consecutive ones ending at c
        return c - ones + 1;
    }
    int ones = leading_ones(hi << (127 - c));
    int rs = c - ones + 1;
    if (rs == 64) rs -= leading_ones(lo);          // run crosses the 64 boundary
    return rs;
}

// column of the end of the fg run containing column c (bit c must be set)
__device__ inline int run_end_col(ull lo, ull hi, int c) {
    if (c >= 64) {
        return c + trailing_ones(hi >> (c - 64)) - 1;
    }
    int e = c + trailing_ones(lo >> c) - 1;
    if (e == 63) e += trailing_ones(hi);           // run crosses the 64 boundary
    return e;
}

// 0-based index of the run starting at column cs (cs must be a run start)
__device__ inline int run_index(ull rs_lo, ull rs_hi, int cs) {
    if (cs < 64)  return __popcll(rs_lo & ((1ULL << cs) - 1ULL));
    if (cs == 64) return __popcll(rs_lo);
    return __popcll(rs_lo) + __popcll(rs_hi & ((1ULL << (cs - 64)) - 1ULL));
}

__device__ inline void top3_ins(float s, int id, int x,
    float& s0, float& s1, float& s2,
    int& i0, int& i1, int& i2,
    int& x0, int& x1, int& x2)
{
    if (x < 0) return;
    if (s > s0 || (s == s0 && id < i0)) {
        s2 = s1; i2 = i1; x2 = x1;
        s1 = s0; i1 = i0; x1 = x0;
        s0 = s;  i0 = id; x0 = x;
    } else if (s > s1 || (s == s1 && id < i1)) {
        s2 = s1; i2 = i1; x2 = x1;
        s1 = s;  i1 = id; x1 = x;
    } else if (s > s2 || (s == s2 && id < i2)) {
        s2 = s;  i2 = id; x2 = x;
    }
}

// ---------------------------------------------------------------------------
// Kernel 1: one block per image. Run-based union-find CCL + per-component
// stats + top-3 selection + bbox — ALL in LDS. Zero global atomics.
//
// R4 change: the vertical-union pass (P2) is now a 7-level hierarchical
// row-group merge tree instead of all-rows-at-once. At p~0.5 the image has
// one giant component; with all 127 boundaries processed concurrently every
// union funnels into ONE root -> ~thousands of serialized atomicCAS retries,
// each paying a ~120-cycle dependent volatile-LDS find chain (the ~700k-cycle
// hot spot). Level k merges 2^k-row groups pairwise: run ids are row-major
// and links go high->low, so before level k each component is confined to
// its group -> boundaries at one level touch DISJOINT run-id ranges ->
// zero cross-boundary CAS contention; within-boundary contention <= ~32
// unions. Union set and dedup predicate are unchanged -> identical roots
// (root = min run id, order-independent).
// ---------------------------------------------------------------------------

__global__ __launch_bounds__(1024) void ccl_kernel(
    const float* __restrict__ prob, int* __restrict__ bbox)
{
    __shared__ int parent[NRUN];          // 32 KB
    __shared__ ull rowmask[HH][2];        // 2 KB
    __shared__ int   lcnt[NCOMP];         // 16 KB
    __shared__ float lconf[NCOMP];        // 16 KB
    __shared__ int lminr[NCOMP], lmaxr[NCOMP];
    __shared__ int lminc[NCOMP], lmaxc[NCOMP];
    __shared__ int lmaxid[NCOMP];         // 5 x 16 KB
    __shared__ int snroots;
    __shared__ float wss[48];
    __shared__ int wid_[48], wrx[48];

    const int b = blockIdx.x;
    const int tid = threadIdx.x;
    const float* p = prob + (size_t)b * HW;

    if (tid == 0) snroots = 0;

    // P0: per-row fg bitmasks via ballot (each wave = half a row, coalesced)
    #pragma unroll
    for (int k = 0; k < HW / 1024; ++k) {
        int i = k * 1024 + tid;
        ull m = __ballot(p[i] > 0.5f);
        if ((tid & 63) == 0) rowmask[i >> 7][(i >> 6) & 1] = m;
    }
    // init LDS stats (not read until P4; no extra barrier needed)
    for (int j = tid; j < NCOMP; j += 1024) {
        lcnt[j] = 0; lconf[j] = 0.f;
        lminr[j] = INT_MAX; lmaxr[j] = -1;
        lminc[j] = INT_MAX; lmaxc[j] = -1;
        lmaxid[j] = 0;
    }
    __syncthreads();

    // P1: parent self-init over valid run-id space
    for (int rid = tid; rid < NRUN; rid += 1024) {
        int r = rid >> 6;
        ull lo = rowmask[r][0], hi = rowmask[r][1];
        ull rs_lo = lo & ~(lo << 1);
        ull rs_hi = hi & ~((hi << 1) | (lo >> 63));
        int nruns = __popcll(rs_lo) + __popcll(rs_hi);
        if ((rid & 63) < nruns) parent[rid] = rid;
    }
    __syncthreads();

    // P2: hierarchical vertical merge. Level lev merges row-groups of size
    // 2^lev pairwise at boundary rows r = (2*j+1)<<lev, j = 0..(64>>lev)-1.
    // Contact detection + leftmost-contact dedup identical to the flat pass.
    for (int lev = 0; lev < 7; ++lev) {
        const int nbound = 64 >> lev;        // boundaries this level
        const int npix = nbound << 7;        // 128 pixels per boundary row
        for (int base = 0; base < npix; base += 1024) {
            int i = base + tid;
            if (i >= npix) continue;                 // no barrier inside: safe
            int r = ((((i >> 7) << 1) + 1) << lev);  // boundary row (merge r-1, r)
            int c = i & 127;
            ull lo = rowmask[r][0], hi = rowmask[r][1];
            if (!getbit2(lo, hi, c)) continue;
            ull ulo = rowmask[r - 1][0], uhi = rowmask[r - 1][1];
            int l  = (c > 0)   ? getbit2(lo, hi, c - 1) : 0;
            int rt = (c < 127) ? getbit2(lo, hi, c + 1) : 0;
            int up = getbit2(ulo, uhi, c);
            int ul = (c > 0)   ? getbit2(ulo, uhi, c - 1) : 0;
            int ur = (c < 127) ? getbit2(ulo, uhi, c + 1) : 0;
            bool u1 = up && !(l && ul);          // leftmost-contact dedup
            bool u2 = !up && ul && !l;
            bool u3 = !up && ur && !rt;
            if (!(u1 | u2 | u3)) continue;
            ull rs_lo = lo & ~(lo << 1),   rs_hi = hi & ~((hi << 1) | (lo >> 63));
            ull urs_lo = ulo & ~(ulo << 1), urs_hi = uhi & ~((uhi << 1) | (ulo >> 63));
            int cs = run_start_col(lo, hi, c);
            int rid = (r << 6) + run_index(rs_lo, rs_hi, cs);
            int ub = (r - 1) << 6;
            if (u1) uf_union(parent, rid, ub + run_index(urs_lo, urs_hi, run_start_col(ulo, uhi, c)));
            if (u2) uf_union(parent, rid, ub + run_index(urs_lo, urs_hi, run_start_col(ulo, uhi, c - 1)));
            if (u3) uf_union(parent, rid, ub + run_index(urs_lo, urs_hi, run_start_col(ulo, uhi, c + 1)));
        }
        __syncthreads();   // level k complete before level k+1 crosses groups
    }

    // P3: flatten all runs to their root
    for (int rid = tid; rid < NRUN; rid += 1024) {
        int r = rid >> 6;
        ull lo = rowmask[r][0], hi = rowmask[r][1];
        ull rs_lo = lo & ~(lo << 1);
        ull rs_hi = hi & ~((hi << 1) | (lo >> 63));
        int nruns = __popcll(rs_lo) + __popcll(rs_hi);
        if ((rid & 63) < nruns) parent[rid] = uf_find(parent, rid);
    }
    __syncthreads();
    // P3b: roots claim dense indices; parent[root] = NRUN + denseIdx
    for (int rid = tid; rid < NRUN; rid += 1024) {
        int r = rid >> 6;
        ull lo = rowmask[r][0], hi = rowmask[r][1];
        ull rs_lo = lo & ~(lo << 1);
        ull rs_hi = hi & ~((hi << 1) | (lo >> 63));
        int nruns = __popcll(rs_lo) + __popcll(rs_hi);
        if ((rid & 63) < nruns && parent[rid] == rid) {
            int idx = atomicAdd(&snroots, 1);
            parent[rid] = NRUN + idx;
        }
    }
    __syncthreads();

    // P4: per-run stats into LDS dense arrays, with per-thread run
    // aggregation (thread = one 16-col window of one row)
    {
        int row = tid >> 3;
        int w0 = (tid & 7) * 16;
        ull lo = rowmask[row][0], hi = rowmask[row][1];
        ull rs_lo = lo & ~(lo << 1);
        ull rs_hi = hi & ~((hi << 1) | (lo >> 63));
        ull seg = ((w0 < 64) ? (rs_lo >> w0) : (rs_hi >> (w0 - 64))) & 0xFFFFULL;
        int curIdx = -1, aCnt = 0, aMinc = 0, aMaxc = 0, aMaxid = 0;
        float aConf = 0.f;
        while (seg) {
            int c = w0 + (__ffsll(seg) - 1);
            seg &= seg - 1;
            int e = run_end_col(lo, hi, c);
            int rid = (row << 6) + run_index(rs_lo, rs_hi, c);
            int v = parent[rid];
            int idx = (v >= NRUN) ? (v - NRUN) : (parent[v] - NRUN);
            float s = 0.f;
            for (int j = c; j <= e; ++j) s += p[(row << 7) + j];
            if (idx == curIdx) {
                aCnt += e - c + 1; aConf += s;
                aMaxc = e; aMaxid = (row << 7) + e + 1;
            } else {
                if (curIdx >= 0) {
                    atomicAdd(&lcnt[curIdx], aCnt);
                    atomicAdd(&lconf[curIdx], aConf);
                    atomicMin(&lminr[curIdx], row);
                    atomicMax(&lmaxr[curIdx], row);
                    atomicMin(&lminc[curIdx], aMinc);
                    atomicMax(&lmaxc[curIdx], aMaxc);
                    atomicMax(&lmaxid[curIdx], aMaxid);
                }
                curIdx = idx; aCnt = e - c + 1; aConf = s;
                aMinc = c; aMaxc = e; aMaxid = (row << 7) + e + 1;
            }
        }
        if (curIdx >= 0) {
            atomicAdd(&lcnt[curIdx], aCnt);
            atomicAdd(&lconf[curIdx], aConf);
            atomicMin(&lminr[curIdx], row);
            atomicMax(&lmaxr[curIdx], row);
            atomicMin(&lminc[curIdx], aMinc);
            atomicMax(&lmaxc[curIdx], aMaxc);
            atomicMax(&lmaxid[curIdx], aMaxid);
        }
    }
    __syncthreads();

    // P5: top-3 by (mean_conf desc, segment-id asc) — thread scan, wave
    // shfl_xor butterfly merge, tid0 final merge + K rules + bbox write
    const int n = snroots;
    float s0 = -INFINITY, s1 = -INFINITY, s2 = -INFINITY;
    int i0 = INT_MAX, i1 = INT_MAX, i2 = INT_MAX;
    int x0 = -1, x1 = -1, x2 = -1;
    for (int j = tid; j < n; j += 1024) {
        float s = lconf[j] / (float)lcnt[j];
        top3_ins(s, lmaxid[j], j, s0, s1, s2, i0, i1, i2, x0, x1, x2);
    }
    for (int off = 32; off; off >>= 1) {
        float bs0 = __shfl_xor(s0, off), bs1 = __shfl_xor(s1, off), bs2 = __shfl_xor(s2, off);
        int bi0 = __shfl_xor(i0, off), bi1 = __shfl_xor(i1, off), bi2 = __shfl_xor(i2, off);
        int bx0 = __shfl_xor(x0, off), bx1 = __shfl_xor(x1, off), bx2 = __shfl_xor(x2, off);
        top3_ins(bs0, bi0, bx0, s0, s1, s2, i0, i1, i2, x0, x1, x2);
        top3_ins(bs1, bi1, bx1, s0, s1, s2, i0, i1, i2, x0, x1, x2);
        top3_ins(bs2, bi2, bx2, s0, s1, s2, i0, i1, i2, x0, x1, x2);
    }
    if ((tid & 63) == 0) {
        int w = tid >> 6;
        wss[w * 3 + 0] = s0; wid_[w * 3 + 0] = i0; wrx[w * 3 + 0] = x0;
        wss[w * 3 + 1] = s1; wid_[w * 3 + 1] = i1; wrx[w * 3 + 1] = x1;
        wss[w * 3 + 2] = s2; wid_[w * 3 + 2] = i2; wrx[w * 3 + 2] = x2;
    }
    __syncthreads();

    if (tid == 0) {
        float t0 = -INFINITY, t1 = -INFINITY, t2 = -INFINITY;
        int ti0 = INT_MAX, ti1 = INT_MAX, ti2 = INT_MAX;
        int tx0 = -1, tx1 = -1, tx2 = -1;
        for (int t = 0; t < 48; ++t)
            top3_ins(wss[t], wid_[t], wrx[t], t0, t1, t2, ti0, ti1, ti2, tx0, tx1, tx2);
        int K = n;
        int roots[3];
        if (K >= 3)      { roots[0] = tx0; roots[1] = tx1; roots[2] = tx2; }
        else if (K == 2) { roots[0] = tx0; roots[1] = tx0; roots[2] = tx1; }
        else             { roots[0] = tx0; roots[1] = tx0; roots[2] = tx0; }
        for (int slot = 0; slot < 3; ++slot) {
            int mr, h, mc, w;
            if (K == 0) { mr = 0; h = HH; mc = 0; w = WW_; }
            else {
                int rt = roots[slot];
                mr = lminr[rt]; h = lmaxr[rt] + 1 - mr;
                mc = lminc[rt]; w = lmaxc[rt] + 1 - mc;
            }
            int* o = bbox + (b * 3 + slot) * 4;
            o[0] = mr; o[1] = h; o[2] = mc; o[3] = w;
        }
    }
}

// ---------------------------------------------------------------------------
// Kernel 2: nearest-neighbor crop-resize gather. One float4 store per thread.
// out[b, slot*192+c, y, x] = feat[b, c, mr + (y*h)>>6, mc + (x*w)>>6]
// ---------------------------------------------------------------------------

__global__ __launch_bounds__(256) void crop_kernel(
    const float* __restrict__ feat, const int* __restrict__ bbox,
    float* __restrict__ out)
{
    const int gid = blockIdx.x * 256 + threadIdx.x;   // 9,437,184 total
    const int x4 = gid & 15;
    const int y  = (gid >> 4) & 63;
    const int t  = gid >> 10;        // (b*3+slot)*192 + c, 0..9215
    const int c  = t % CF;
    const int bs = t / CF;           // b*3+slot, 0..47
    const int* bb = bbox + bs * 4;
    const int mr = bb[0], h = bb[1], mc = bb[2], w = bb[3];
    const int r = mr + ((y * h) >> 6);
    const int bimg = bs / 3;
    const float* row = feat + (((size_t)bimg * CF + c) * HH + r) * WW_;
    const int x = x4 * 4;
    vf4 v;
    v.x = row[mc + (((x + 0) * w) >> 6)];
    v.y = row[mc + (((x + 1) * w) >> 6)];
    v.z = row[mc + (((x + 2) * w) >> 6)];
    v.w = row[mc + (((x + 3) * w) >> 6)];
    __builtin_nontemporal_store(v, (vf4*)out + gid);  // streaming store
}

// ---------------------------------------------------------------------------

extern "C" void kernel_launch(void* const* d_in, const int* in_sizes, int n_in,
                              void* d_out, int out_size, void* d_ws, size_t ws_size,
                              hipStream_t stream) {
    const float* prob = (const float*)d_in[0];   // [16,1,128,128]
    const float* feat = (const float*)d_in[1];   // [16,192,128,128]
    float* out = (float*)d_out;                  // [16,576,64,64]

    int* bbox = (int*)d_ws;                      // [16][3][4] ints, fully written

    hipLaunchKernelGGL(ccl_kernel, dim3(NB), dim3(1024), 0, stream,
                       prob, bbox);
    const int total4 = NB * 3 * CF * H2 * (W2 / 4);   // 9,437,184
    hipLaunchKernelGGL(crop_kernel, dim3(total4 / 256), dim3(256), 0, stream,
                       feat, bbox, out);
}

// Round 2
// 351.707 us; speedup vs baseline: 1.1217x; 1.1217x over previous
//
#include <hip/hip_runtime.h>
#include <limits.h>

#define HH 128
#define WW_ 128
#define HW 16384
#define NB 16
#define CF 192
#define H2 64
#define W2 64

#define SH 16          // stripe height
#define NSPI 8         // stripes per image
#define NST 128        // total stripe blocks
#define SC 512         // max components per 16x128 stripe (ceil(16/2)*ceil(128/2))
#define NCI 4096       // component handles per image = NSPI*SC
#define NLRUN 1024     // local run-id slots = SH*64

typedef float vf4 __attribute__((ext_vector_type(4)));
typedef unsigned long long ull;

// ---------------------------------------------------------------------------
// Union-find on an LDS parent array. Links always go high->low id -> chains
// strictly decrease -> concurrent path halving is safe and terminating.
// ---------------------------------------------------------------------------

__device__ inline int uf_find(int* par, int x) {
    volatile int* vp = (volatile int*)par;
    int p = vp[x];
    while (p != x) {
        int g = vp[p];
        vp[x] = g;      // path halving: writes an ancestor, safe under races
        x = g;
        p = vp[x];
    }
    return x;
}

__device__ inline void uf_union(int* par, int a, int b) {
    int ra = uf_find(par, a);
    int rb = uf_find(par, b);
    while (ra != rb) {
        if (ra < rb) { int t = ra; ra = rb; rb = t; }   // link larger -> smaller
        int old = atomicCAS(&par[ra], ra, rb);
        if (old == ra) return;
        ra = uf_find(par, old);
        rb = uf_find(par, rb);
    }
}

// ---------------------------------------------------------------------------
// 128-bit row mask helpers (lo = cols 0..63, hi = cols 64..127)
// ---------------------------------------------------------------------------

__device__ inline int getbit2(ull lo, ull hi, int c) {
    return (int)(((c < 64) ? (lo >> c) : (hi >> (c - 64))) & 1ULL);
}

__device__ inline int leading_ones(ull v) {
    ull nv = ~v;
    return (nv == 0ULL) ? 64 : __clzll(nv);
}

__device__ inline int trailing_ones(ull v) {
    ull nv = ~v;
    return (nv == 0ULL) ? 64 : (__ffsll(nv) - 1);
}

// column of the start of the fg run containing column c (bit c must be set)
__device__ inline int run_start_col(ull lo, ull hi, int c) {
    if (c < 64) {
        int ones = leading_ones(lo << (63 - c));   // consecutive ones ending at c
        return c - ones + 1;
    }
    int ones = leading_ones(hi << (127 - c));
    int rs = c - ones + 1;
    if (rs == 64) rs -= leading_ones(lo);          // run crosses the 64 boundary
    return rs;
}

// 0-based index of the run starting at column cs (cs must be a run start)
__device__ inline int run_index(ull rs_lo, ull rs_hi, int cs) {
    if (cs < 64)  return __popcll(rs_lo & ((1ULL << cs) - 1ULL));
    if (cs == 64) return __popcll(rs_lo);
    return __popcll(rs_lo) + __popcll(rs_hi & ((1ULL << (cs - 64)) - 1ULL));
}

__device__ inline void top3_ins(float s, int id, int x,
    float& s0, float& s1, float& s2,
    int& i0, int& i1, int& i2,
    int& x0, int& x1, int& x2)
{
    if (x < 0) return;
    if (s > s0 || (s == s0 && id < i0)) {
        s2 = s1; i2 = i1; x2 = x1;
        s1 = s0; i1 = i0; x1 = x0;
        s0 = s;  i0 = id; x0 = x;
    } else if (s > s1 || (s == s1 && id < i1)) {
        s2 = s1; i2 = i1; x2 = x1;
        s1 = s;  i1 = id; x1 = x;
    } else if (s > s2 || (s == s2 && id < i2)) {
        s2 = s;  i2 = id; x2 = x;
    }
}

// ---------------------------------------------------------------------------
// Kernel A: one block per 16-row stripe (128 blocks = 8 stripes x 16 images).
// Local run-based union-find CCL + per-component stats in LDS; writes a
// compact component table + boundary-row run->component maps to global.
// Pixel values are kept in registers from the load pass (no global re-read).
// ---------------------------------------------------------------------------

__global__ __launch_bounds__(256) void stripe_ccl(
    const float* __restrict__ prob,
    int* __restrict__ nlocg, int* __restrict__ gcnt, float* __restrict__ gconf,
    int* __restrict__ gminr, int* __restrict__ gmaxr,
    int* __restrict__ gminc, int* __restrict__ gmaxc,
    int* __restrict__ gmaxid, int* __restrict__ brun, ull* __restrict__ bmask)
{
    __shared__ ull rowm[SH][2];            // 256 B
    __shared__ unsigned char m8[256];      // per-thread 8-px masks
    __shared__ int parent[NLRUN];          // 4 KB
    __shared__ int   lcnt[SC];             // per-component stats: 14 KB total
    __shared__ float lconf[SC];
    __shared__ int lminr[SC], lmaxr[SC], lminc[SC], lmaxc[SC], lmaxid[SC];
    __shared__ int snloc;

    const int g = blockIdx.x;
    const int b = g >> 3, s = g & 7;
    const int row0 = s * SH;
    const int tid = threadIdx.x;
    const int row = tid >> 4;              // 0..15 (stripe-local)
    const int w0 = (tid & 15) * 8;         // 8-col window per thread

    if (tid == 0) snloc = 0;

    // P0: load 8 pixels into registers, build masks
    const float* p = prob + (size_t)b * HW + (size_t)((row0 + row) << 7) + w0;
    vf4 va = *(const vf4*)p;
    vf4 vb = *(const vf4*)(p + 4);
    int mask8 = 0;
    mask8 |= (va.x > 0.5f) << 0; mask8 |= (va.y > 0.5f) << 1;
    mask8 |= (va.z > 0.5f) << 2; mask8 |= (va.w > 0.5f) << 3;
    mask8 |= (vb.x > 0.5f) << 4; mask8 |= (vb.y > 0.5f) << 5;
    mask8 |= (vb.z > 0.5f) << 6; mask8 |= (vb.w > 0.5f) << 7;
    m8[tid] = (unsigned char)mask8;
    for (int j = tid; j < SC; j += 256) {
        lcnt[j] = 0; lconf[j] = 0.f;
        lminr[j] = INT_MAX; lmaxr[j] = -1;
        lminc[j] = INT_MAX; lmaxc[j] = -1;
        lmaxid[j] = 0;
    }
    __syncthreads();
    if (tid < 32) {                        // assemble 64-bit half-row masks
        int r = tid >> 1, half = tid & 1;
        ull v = 0;
        #pragma unroll
        for (int k2 = 0; k2 < 8; ++k2)
            v |= (ull)m8[(r << 4) + (half << 3) + k2] << (k2 * 8);
        rowm[r][half] = v;
    }
    __syncthreads();

    // P1: parent self-init over valid local run ids
    for (int rid = tid; rid < NLRUN; rid += 256) {
        int r = rid >> 6;
        ull lo = rowm[r][0], hi = rowm[r][1];
        ull rs_lo = lo & ~(lo << 1);
        ull rs_hi = hi & ~((hi << 1) | (lo >> 63));
        int nruns = __popcll(rs_lo) + __popcll(rs_hi);
        if ((rid & 63) < nruns) parent[rid] = rid;
    }
    __syncthreads();

    // P2: vertical unions inside the stripe (local rows 1..15)
    for (int i = tid; i < (SH - 1) * 128; i += 256) {
        int r = 1 + (i >> 7), c = i & 127;
        ull lo = rowm[r][0], hi = rowm[r][1];
        if (!getbit2(lo, hi, c)) continue;
        ull ulo = rowm[r - 1][0], uhi = rowm[r - 1][1];
        int l  = (c > 0)   ? getbit2(lo, hi, c - 1) : 0;
        int rt = (c < 127) ? getbit2(lo, hi, c + 1) : 0;
        int up = getbit2(ulo, uhi, c);
        int ul = (c > 0)   ? getbit2(ulo, uhi, c - 1) : 0;
        int ur = (c < 127) ? getbit2(ulo, uhi, c + 1) : 0;
        bool u1 = up && !(l && ul);          // leftmost-contact dedup
        bool u2 = !up && ul && !l;
        bool u3 = !up && ur && !rt;
        if (!(u1 | u2 | u3)) continue;
        ull rs_lo = lo & ~(lo << 1),   rs_hi = hi & ~((hi << 1) | (lo >> 63));
        ull urs_lo = ulo & ~(ulo << 1), urs_hi = uhi & ~((uhi << 1) | (ulo >> 63));
        int cs = run_start_col(lo, hi, c);
        int rid = (r << 6) + run_index(rs_lo, rs_hi, cs);
        int ub = (r - 1) << 6;
        if (u1) uf_union(parent, rid, ub + run_index(urs_lo, urs_hi, run_start_col(ulo, uhi, c)));
        if (u2) uf_union(parent, rid, ub + run_index(urs_lo, urs_hi, run_start_col(ulo, uhi, c - 1)));
        if (u3) uf_union(parent, rid, ub + run_index(urs_lo, urs_hi, run_start_col(ulo, uhi, c + 1)));
    }
    __syncthreads();

    // P3: flatten
    for (int rid = tid; rid < NLRUN; rid += 256) {
        int r = rid >> 6;
        ull lo = rowm[r][0], hi = rowm[r][1];
        ull rs_lo = lo & ~(lo << 1);
        ull rs_hi = hi & ~((hi << 1) | (lo >> 63));
        int nruns = __popcll(rs_lo) + __popcll(rs_hi);
        if ((rid & 63) < nruns) parent[rid] = uf_find(parent, rid);
    }
    __syncthreads();
    // P3b: roots claim dense local indices
    for (int rid = tid; rid < NLRUN; rid += 256) {
        int r = rid >> 6;
        ull lo = rowm[r][0], hi = rowm[r][1];
        ull rs_lo = lo & ~(lo << 1);
        ull rs_hi = hi & ~((hi << 1) | (lo >> 63));
        int nruns = __popcll(rs_lo) + __popcll(rs_hi);
        if ((rid & 63) < nruns && parent[rid] == rid) {
            int idx = atomicAdd(&snloc, 1);
            parent[rid] = NLRUN + idx;
        }
    }
    __syncthreads();

    // P4: per-thread window stats from registers (each pixel counted once)
    {
        ull lo = rowm[row][0], hi = rowm[row][1];
        ull rs_lo = lo & ~(lo << 1);
        ull rs_hi = hi & ~((hi << 1) | (lo >> 63));
        const float vv[8] = {va.x, va.y, va.z, va.w, vb.x, vb.y, vb.z, vb.w};
        const int imr = row0 + row;
        int curIdx = -1, aCnt = 0, aMinc = 0, aMaxc = 0, aMaxid = 0;
        float aConf = 0.f;
        bool prevfg = false;
        #pragma unroll
        for (int j = 0; j < 8; ++j) {
            bool fg = (mask8 >> j) & 1;
            if (fg) {
                int c = w0 + j;
                if (!prevfg) {                 // new window-segment: resolve comp
                    int cs = run_start_col(lo, hi, c);
                    int rid = (row << 6) + run_index(rs_lo, rs_hi, cs);
                    int v = parent[rid];
                    int idx = (v >= NLRUN) ? v - NLRUN : parent[v] - NLRUN;
                    if (idx != curIdx) {
                        if (curIdx >= 0) {
                            atomicAdd(&lcnt[curIdx], aCnt);
                            atomicAdd(&lconf[curIdx], aConf);
                            atomicMin(&lminr[curIdx], imr);
                            atomicMax(&lmaxr[curIdx], imr);
                            atomicMin(&lminc[curIdx], aMinc);
                            atomicMax(&lmaxc[curIdx], aMaxc);
                            atomicMax(&lmaxid[curIdx], aMaxid);
                        }
                        curIdx = idx; aCnt = 0; aConf = 0.f;
                        aMinc = c; aMaxc = c; aMaxid = 0;
                    }
                }
                aCnt++; aConf += vv[j]; aMaxc = c;
                aMaxid = (imr << 7) + c + 1;
            }
            prevfg = fg;
        }
        if (curIdx >= 0) {
            atomicAdd(&lcnt[curIdx], aCnt);
            atomicAdd(&lconf[curIdx], aConf);
            atomicMin(&lminr[curIdx], imr);
            atomicMax(&lmaxr[curIdx], imr);
            atomicMin(&lminc[curIdx], aMinc);
            atomicMax(&lmaxc[curIdx], aMaxc);
            atomicMax(&lmaxid[curIdx], aMaxid);
        }
    }
    __syncthreads();

    // P5: export component table + boundary maps
    const int nl = snloc;
    for (int j = tid; j < nl; j += 256) {
        int d = (g << 9) + j;
        gcnt[d] = lcnt[j];  gconf[d] = lconf[j];
        gminr[d] = lminr[j]; gmaxr[d] = lmaxr[j];
        gminc[d] = lminc[j]; gmaxc[d] = lmaxc[j];
        gmaxid[d] = lmaxid[j];
    }
    if (tid == 0) nlocg[g] = nl;
    if (tid < 128) {
        int br = tid >> 6;                 // 0: local row 0, 1: local row 15
        int j = tid & 63;
        int r = br ? (SH - 1) : 0;
        ull lo = rowm[r][0], hi = rowm[r][1];
        ull rs_lo = lo & ~(lo << 1);
        ull rs_hi = hi & ~((hi << 1) | (lo >> 63));
        int nruns = __popcll(rs_lo) + __popcll(rs_hi);
        if (j < nruns) {
            int rid = (r << 6) + j;
            int v = parent[rid];
            brun[(g << 7) + (br << 6) + j] = (v >= NLRUN) ? v - NLRUN : parent[v] - NLRUN;
        }
        if (j == 0) {
            bmask[(g << 2) + (br << 1) + 0] = lo;
            bmask[(g << 2) + (br << 1) + 1] = hi;
        }
    }
}

// ---------------------------------------------------------------------------
// Kernel B: one block per image. Unions only across the 7 stripe boundaries
// (same contact rule, image rows 16k), folds stripe component stats, top-3,
// bbox. Total union set over rows 1..127 identical to the flat version.
// ---------------------------------------------------------------------------

__global__ __launch_bounds__(1024) void merge_kernel(
    const int* __restrict__ nlocg, const int* __restrict__ gcnt,
    const float* __restrict__ gconf,
    const int* __restrict__ gminr, const int* __restrict__ gmaxr,
    const int* __restrict__ gminc, const int* __restrict__ gmaxc,
    const int* __restrict__ gmaxid, const int* __restrict__ brun,
    const ull* __restrict__ bmask, int* __restrict__ bbox)
{
    __shared__ int parent2[NCI];          // 16 KB
    __shared__ int   cnt2[NCI];           // 7 x 16 KB stats
    __shared__ float conf2[NCI];
    __shared__ int minr2[NCI], maxr2[NCI], minc2[NCI], maxc2[NCI], maxid2[NCI];
    __shared__ int sK;
    __shared__ float wss[48];
    __shared__ int wid_[48], wrx[48];

    const int b = blockIdx.x;
    const int tid = threadIdx.x;
    if (tid == 0) sK = 0;
    for (int i = tid; i < NCI; i += 1024) { parent2[i] = i; cnt2[i] = 0; }
    __syncthreads();

    // load stripe component tables into handle space s*512+j
    for (int s = 0; s < NSPI; ++s) {
        int g = (b << 3) + s;
        int n = nlocg[g];
        for (int j = tid; j < n; j += 1024) {
            int d = (s << 9) + j, e = (g << 9) + j;
            cnt2[d] = gcnt[e];  conf2[d] = gconf[e];
            minr2[d] = gminr[e]; maxr2[d] = gmaxr[e];
            minc2[d] = gminc[e]; maxc2[d] = gmaxc[e];
            maxid2[d] = gmaxid[e];
        }
    }
    __syncthreads();

    // boundary unions: boundary k joins stripe k-1 (its row 15) with stripe k
    // (its row 0) at image row 16k
    for (int i = tid; i < 7 * 128; i += 1024) {
        int k = 1 + (i >> 7), c = i & 127;
        int gLo = (b << 3) + k, gUp = gLo - 1;
        ull lo = bmask[(gLo << 2) + 0], hi = bmask[(gLo << 2) + 1];
        if (!getbit2(lo, hi, c)) continue;
        ull ulo = bmask[(gUp << 2) + 2], uhi = bmask[(gUp << 2) + 3];
        int l  = (c > 0)   ? getbit2(lo, hi, c - 1) : 0;
        int rt = (c < 127) ? getbit2(lo, hi, c + 1) : 0;
        int up = getbit2(ulo, uhi, c);
        int ul = (c > 0)   ? getbit2(ulo, uhi, c - 1) : 0;
        int ur = (c < 127) ? getbit2(ulo, uhi, c + 1) : 0;
        bool u1 = up && !(l && ul);
        bool u2 = !up && ul && !l;
        bool u3 = !up && ur && !rt;
        if (!(u1 | u2 | u3)) continue;
        ull rs_lo = lo & ~(lo << 1),   rs_hi = hi & ~((hi << 1) | (lo >> 63));
        ull urs_lo = ulo & ~(ulo << 1), urs_hi = uhi & ~((uhi << 1) | (ulo >> 63));
        int cs = run_start_col(lo, hi, c);
        int myid = (k << 9) + brun[(gLo << 7) + run_index(rs_lo, rs_hi, cs)];
        int ubase = (k - 1) << 9;
        if (u1) uf_union(parent2, myid, ubase + brun[(gUp << 7) + 64 + run_index(urs_lo, urs_hi, run_start_col(ulo, uhi, c))]);
        if (u2) uf_union(parent2, myid, ubase + brun[(gUp << 7) + 64 + run_index(urs_lo, urs_hi, run_start_col(ulo, uhi, c - 1))]);
        if (u3) uf_union(parent2, myid, ubase + brun[(gUp << 7) + 64 + run_index(urs_lo, urs_hi, run_start_col(ulo, uhi, c + 1))]);
    }
    __syncthreads();

    // fold non-root stats into roots (forest fixed; merges target roots only)
    for (int i = tid; i < NCI; i += 1024) {
        if (cnt2[i] > 0) {
            int r = uf_find(parent2, i);
            if (r != i) {
                atomicAdd(&cnt2[r], cnt2[i]);   atomicAdd(&conf2[r], conf2[i]);
                atomicMin(&minr2[r], minr2[i]); atomicMax(&maxr2[r], maxr2[i]);
                atomicMin(&minc2[r], minc2[i]); atomicMax(&maxc2[r], maxc2[i]);
                atomicMax(&maxid2[r], maxid2[i]);
            }
        }
    }
    __syncthreads();

    // top-3 by (mean_conf desc, id asc) over roots; K = root count
    float s0 = -INFINITY, s1 = -INFINITY, s2 = -INFINITY;
    int i0 = INT_MAX, i1 = INT_MAX, i2 = INT_MAX;
    int x0 = -1, x1 = -1, x2 = -1;
    int kc = 0;
    for (int i = tid; i < NCI; i += 1024) {
        if (parent2[i] == i && cnt2[i] > 0) {
            ++kc;
            float sc = conf2[i] / (float)cnt2[i];
            top3_ins(sc, maxid2[i], i, s0, s1, s2, i0, i1, i2, x0, x1, x2);
        }
    }
    for (int off = 32; off; off >>= 1) kc += __shfl_xor(kc, off);
    if ((tid & 63) == 0) atomicAdd(&sK, kc);
    for (int off = 32; off; off >>= 1) {
        float bs0 = __shfl_xor(s0, off), bs1 = __shfl_xor(s1, off), bs2 = __shfl_xor(s2, off);
        int bi0 = __shfl_xor(i0, off), bi1 = __shfl_xor(i1, off), bi2 = __shfl_xor(i2, off);
        int bx0 = __shfl_xor(x0, off), bx1 = __shfl_xor(x1, off), bx2 = __shfl_xor(x2, off);
        top3_ins(bs0, bi0, bx0, s0, s1, s2, i0, i1, i2, x0, x1, x2);
        top3_ins(bs1, bi1, bx1, s0, s1, s2, i0, i1, i2, x0, x1, x2);
        top3_ins(bs2, bi2, bx2, s0, s1, s2, i0, i1, i2, x0, x1, x2);
    }
    if ((tid & 63) == 0) {
        int w = tid >> 6;
        wss[w * 3 + 0] = s0; wid_[w * 3 + 0] = i0; wrx[w * 3 + 0] = x0;
        wss[w * 3 + 1] = s1; wid_[w * 3 + 1] = i1; wrx[w * 3 + 1] = x1;
        wss[w * 3 + 2] = s2; wid_[w * 3 + 2] = i2; wrx[w * 3 + 2] = x2;
    }
    __syncthreads();

    if (tid == 0) {
        float t0 = -INFINITY, t1 = -INFINITY, t2 = -INFINITY;
        int ti0 = INT_MAX, ti1 = INT_MAX, ti2 = INT_MAX;
        int tx0 = -1, tx1 = -1, tx2 = -1;
        for (int t = 0; t < 48; ++t)
            top3_ins(wss[t], wid_[t], wrx[t], t0, t1, t2, ti0, ti1, ti2, tx0, tx1, tx2);
        int K = sK;
        int roots[3];
        if (K >= 3)      { roots[0] = tx0; roots[1] = tx1; roots[2] = tx2; }
        else if (K == 2) { roots[0] = tx0; roots[1] = tx0; roots[2] = tx1; }
        else             { roots[0] = tx0; roots[1] = tx0; roots[2] = tx0; }
        for (int slot = 0; slot < 3; ++slot) {
            int mr, h, mc, w;
            if (K == 0) { mr = 0; h = HH; mc = 0; w = WW_; }
            else {
                int rt = roots[slot];
                mr = minr2[rt]; h = maxr2[rt] + 1 - mr;
                mc = minc2[rt]; w = maxc2[rt] + 1 - mc;
            }
            int* o = bbox + (b * 3 + slot) * 4;
            o[0] = mr; o[1] = h; o[2] = mc; o[3] = w;
        }
    }
}

// ---------------------------------------------------------------------------
// Kernel 3: nearest-neighbor crop-resize gather. One float4 store per thread.
// ---------------------------------------------------------------------------

__global__ __launch_bounds__(256) void crop_kernel(
    const float* __restrict__ feat, const int* __restrict__ bbox,
    float* __restrict__ out)
{
    const int gid = blockIdx.x * 256 + threadIdx.x;   // 9,437,184 total
    const int x4 = gid & 15;
    const int y  = (gid >> 4) & 63;
    const int t  = gid >> 10;        // (b*3+slot)*192 + c, 0..9215
    const int c  = t % CF;
    const int bs = t / CF;           // b*3+slot, 0..47
    const int* bb = bbox + bs * 4;
    const int mr = bb[0], h = bb[1], mc = bb[2], w = bb[3];
    const int r = mr + ((y * h) >> 6);
    const int bimg = bs / 3;
    const float* row = feat + (((size_t)bimg * CF + c) * HH + r) * WW_;
    const int x = x4 * 4;
    vf4 v;
    v.x = row[mc + (((x + 0) * w) >> 6)];
    v.y = row[mc + (((x + 1) * w) >> 6)];
    v.z = row[mc + (((x + 2) * w) >> 6)];
    v.w = row[mc + (((x + 3) * w) >> 6)];
    __builtin_nontemporal_store(v, (vf4*)out + gid);  // streaming store
}

// ---------------------------------------------------------------------------

extern "C" void kernel_launch(void* const* d_in, const int* in_sizes, int n_in,
                              void* d_out, int out_size, void* d_ws, size_t ws_size,
                              hipStream_t stream) {
    const float* prob = (const float*)d_in[0];   // [16,1,128,128]
    const float* feat = (const float*)d_in[1];   // [16,192,128,128]
    float* out = (float*)d_out;                  // [16,576,64,64]

    int* ws = (int*)d_ws;
    int* bbox   = ws;                            // 192 ints
    int* nlocg  = ws + 192;                      // 128
    int* gcnt   = ws + 320;                      // 7 arrays x 128*512
    float* gconf = (float*)(ws + 320 + 1 * 65536);
    int* gminr  = ws + 320 + 2 * 65536;
    int* gmaxr  = ws + 320 + 3 * 65536;
    int* gminc  = ws + 320 + 4 * 65536;
    int* gmaxc  = ws + 320 + 5 * 65536;
    int* gmaxid = ws + 320 + 6 * 65536;
    int* brun   = ws + 320 + 7 * 65536;          // 128*2*64
    ull* bmask  = (ull*)(ws + 320 + 7 * 65536 + 16384);  // 128*2*2 ulls

    hipLaunchKernelGGL(stripe_ccl, dim3(NST), dim3(256), 0, stream,
                       prob, nlocg, gcnt, gconf, gminr, gmaxr, gminc, gmaxc,
                       gmaxid, brun, bmask);
    hipLaunchKernelGGL(merge_kernel, dim3(NB), dim3(1024), 0, stream,
                       nlocg, gcnt, gconf, gminr, gmaxr, gminc, gmaxc,
                       gmaxid, brun, bmask, bbox);
    const int total4 = NB * 3 * CF * H2 * (W2 / 4);   // 9,437,184
    hipLaunchKernelGGL(crop_kernel, dim3(total4 / 256), dim3(256), 0, stream,
                       feat, bbox, out);
}